// Round 1
// baseline (81.266 us; speedup 1.0000x reference)
//
#include <hip/hip_runtime.h>
#include <math.h>

// Problem constants (from reference setup_inputs)
constexpr int Bb = 128;   // batches
constexpr int Nn = 64;    // events per sequence
constexpr int Hh = 128;   // head events
constexpr int Gg = 4000;  // grid points
constexpr float  TOLf = 0.5f;
constexpr double RESd = 0.03;

constexpr int GBLK  = 16;           // grid blocks per batch, 256 pts each (4096 >= 4000)
constexpr int NGRID = Bb * GBLK;    // 2048
constexpr int NBLK  = NGRID + Bb;   // + 128 event blocks = 2176
constexpr int TSTRIDE = 72;         // per-batch fp64 table stride in elements

constexpr int NKEY = 3 * Nn + Hh;   // 320 breakpoints per batch
constexpr int BPS  = 512;           // padded breakpoint array length (pow2 for search)
constexpr int PAYS = 336;           // payload stride (NKEY+1 = 321 used)
constexpr float BIGF = 1.0e30f;

// ---------------------------------------------------------------------------
// Branchless lower/upper bounds over sorted LDS arrays.
// ---------------------------------------------------------------------------
__device__ __forceinline__ int lb64(const float* __restrict__ a, float key) {
    int lo = (a[31] < key) ? 32 : 0;
    lo += (a[lo + 15] < key) ? 16 : 0;
    lo += (a[lo + 7]  < key) ? 8  : 0;
    lo += (a[lo + 3]  < key) ? 4  : 0;
    lo += (a[lo + 1]  < key) ? 2  : 0;
    lo += (a[lo]      < key) ? 1  : 0;
    lo += (a[lo]      < key) ? 1  : 0;   // resolves count==64
    return lo;
}
__device__ __forceinline__ int ub64(const float* __restrict__ a, float key) {
    int lo = (a[31] <= key) ? 32 : 0;
    lo += (a[lo + 15] <= key) ? 16 : 0;
    lo += (a[lo + 7]  <= key) ? 8  : 0;
    lo += (a[lo + 3]  <= key) ? 4  : 0;
    lo += (a[lo + 1]  <= key) ? 2  : 0;
    lo += (a[lo]      <= key) ? 1  : 0;
    lo += (a[lo]      <= key) ? 1  : 0;
    return lo;
}
__device__ __forceinline__ int lb128(const float* __restrict__ a, float key) {
    int lo = (a[63] < key) ? 64 : 0;
    lo += (a[lo + 31] < key) ? 32 : 0;
    lo += (a[lo + 15] < key) ? 16 : 0;
    lo += (a[lo + 7]  < key) ? 8  : 0;
    lo += (a[lo + 3]  < key) ? 4  : 0;
    lo += (a[lo + 1]  < key) ? 2  : 0;
    lo += (a[lo]      < key) ? 1  : 0;
    lo += (a[lo]      < key) ? 1  : 0;
    return lo;
}
// 512-entry lower bound; array padded with BIGF so count <= 320 < 512
// -> no fixup step needed (a[count] >= key always holds).
__device__ __forceinline__ int lb512(const float* __restrict__ a, float key) {
    int lo = (a[255] < key) ? 256 : 0;
    lo += (a[lo + 127] < key) ? 128 : 0;
    lo += (a[lo + 63]  < key) ? 64  : 0;
    lo += (a[lo + 31]  < key) ? 32  : 0;
    lo += (a[lo + 15]  < key) ? 16  : 0;
    lo += (a[lo + 7]   < key) ? 8   : 0;
    lo += (a[lo + 3]   < key) ? 4   : 0;
    lo += (a[lo + 1]   < key) ? 2   : 0;
    lo += (a[lo]       < key) ? 1   : 0;
    return lo;
}

// float neighbors for positive finite x
__device__ __forceinline__ float predf(float x) { return __uint_as_float(__float_as_uint(x) - 1u); }
__device__ __forceinline__ float succf(float x) { return __uint_as_float(__float_as_uint(x) + 1u); }

// Exact boundary: max float t with fl(t - 0.5f) <= a   (a >= 0).
// Then for any float t:  (t > boundary) <=> (fl(t-0.5f) > a), i.e. the
// reference's strict comparison "a < t - TOL" becomes a pure rank query.
__device__ __forceinline__ float thr_key(float a) {
    float v = a + 0.5f;
    while (v - 0.5f <= a) v = succf(v);   // now fl(v-0.5) > a
    while (v - 0.5f > a)  v = predf(v);   // step back to the max with <=
    return v;
}

// ---------------------------------------------------------------------------
// Kernel A: per-batch prefix tables (wave 0) + merged breakpoint/segment
// payload build (all 320 threads). One block per batch.
//
// Breakpoint keys (strict-rank form; #{key < t} reproduces the reference
// comparison EXACTLY for every float t):
//   list0: pred(thr_key(t1s[j]))  ->  c   = #{t1 < fl(t-0.5)}
//   list1: pred(thr_key(t0s[j]))  ->  c0  = #{t0 < fl(t-0.5)}
//   list2: pred(t0s[j])           ->  c1  = #{t0 <= t}
//   list3: hts[j]                 ->  cnt = #{ht < t}
// Segment s covers t in (bp[s-1], bp[s]]; payload evaluated at t_rep=bp[s].
// Payload: As = w0n*eff*A*e^{-2*tsl},  Qv = w1n*eff*Q*e^{-tsl},  tsl = bp[s-1]
// so per-point  ll = base + ef*(As*ef - Qv),  ef = e^{tsl - t}, and the
// scaled values stay tiny in fp32 (exponent bounded by 2*segment width).
// ---------------------------------------------------------------------------
__global__ __launch_bounds__(320) void precompute_kernel(
    const float* __restrict__ times0, const int* __restrict__ states0,
    const float* __restrict__ times1, const int* __restrict__ states1,
    const float* __restrict__ head_times, const int* __restrict__ head_states,
    const float* __restrict__ base, const float* __restrict__ weights,
    double* __restrict__ Ps_all, double* __restrict__ Qs_all,
    double* __restrict__ SW_all, double* __restrict__ SWP_all,
    int* __restrict__ kT_all,
    float* __restrict__ bp_all, float4* __restrict__ pay_all)
{
    const int b   = blockIdx.x;
    const int tid = threadIdx.x;

    __shared__ float  t0s[Nn], t1s[Nn], hts[Hh];
    __shared__ int    hss[Hh];
    __shared__ float  k0[Nn], k1[Nn], k2[Nn];     // k3 == hts directly
    __shared__ float  bp[BPS];
    __shared__ int    j0s[Nn];
    __shared__ double Ps[Nn + 1], Qs[Nn + 1], SW[Nn + 1], SWP[Nn + 1];
    __shared__ int    kT[Nn + 1];
    __shared__ double wsh2[2];

    float t0 = 0.f, t1 = 0.f; int s0 = 0, s1 = 0;
    double W = 0.0; int j0 = 0;

    // S0: loads
    if (tid < Nn) {
        t0 = times0[b * Nn + tid]; t1 = times1[b * Nn + tid];
        s0 = states0[b * Nn + tid]; s1 = states1[b * Nn + tid];
        t0s[tid] = t0; t1s[tid] = t1;
    } else if (tid < 192) {
        const int k = tid - 64;
        hts[k] = head_times[b * Hh + k];
        hss[k] = head_states[b * Hh + k];
    } else if (tid == 192) {
        const double w0 = (double)weights[0], w1 = (double)weights[1];
        const double mw = fmax(w0, w1);
        const double e0 = exp(w0 - mw), e1 = exp(w1 - mw);
        wsh2[0] = e0 / (e0 + e1);
        wsh2[1] = e1 / (e0 + e1);
    }
    __syncthreads();

    // S1: wave0 scans; other waves build keys + pad bp
    if (tid < Nn) {
        const int i = tid;
        int c = 0;
        #pragma unroll
        for (int j = 0; j < Nn; ++j)
            c += (t0 - t1s[j] >= -TOLf) ? 1 : 0;   // NOT(M) prefix length
        j0 = c;
        j0s[i] = c;
        const double e0 = exp((double)t0);
        double vp = (s1 == 1) ? exp((double)t1) : 0.0;
        double vq = (s0 == 0) ? e0 : 0.0;
        W = (s0 == 1) ? e0 : 0.0;
        double vw = W;
        #pragma unroll
        for (int off = 1; off < 64; off <<= 1) {
            double op = __shfl_up(vp, off, 64);
            double oq = __shfl_up(vq, off, 64);
            double ow = __shfl_up(vw, off, 64);
            if (i >= off) { vp += op; vq += oq; vw += ow; }
        }
        Ps[i + 1] = vp; Qs[i + 1] = vq; SW[i + 1] = vw;
        if (i == 0) { Ps[0] = 0.0; Qs[0] = 0.0; SW[0] = 0.0; SWP[0] = 0.0; }
    } else if (tid < 128) {
        const int j = tid - 64;
        k0[j] = predf(thr_key(t1s[j]));
    } else if (tid < 192) {
        const int j = tid - 128;
        k1[j] = predf(thr_key(t0s[j]));
    } else if (tid < 256) {
        const int j = tid - 192;
        k2[j] = predf(t0s[j]);
    } else {
        for (int k = tid - 256; k < BPS - NKEY; k += 64)
            bp[NKEY + k] = BIGF;
    }
    __syncthreads();

    // S2: wave0 finishes SWP scan, kT, and writes fp64 tables to global
    if (tid < Nn) {
        const int i = tid;
        double vwp = W * Ps[j0];
        #pragma unroll
        for (int off = 1; off < 64; off <<= 1) {
            double o = __shfl_up(vwp, off, 64);
            if (i >= off) vwp += o;
        }
        SWP[i + 1] = vwp;
        int kc = 0;
        #pragma unroll
        for (int j = 0; j < Nn; ++j)
            kc += (j0s[j] <= i) ? 1 : 0;
        kT[i] = kc;
        if (i == 0) kT[Nn] = Nn;

        double* Psg  = Ps_all  + b * TSTRIDE;
        double* Qsg  = Qs_all  + b * TSTRIDE;
        double* SWg  = SW_all  + b * TSTRIDE;
        double* SWPg = SWP_all + b * TSTRIDE;
        int*    kTg  = kT_all  + b * TSTRIDE;
        Psg[i + 1]  = Ps[i + 1];  Qsg[i + 1]  = Qs[i + 1];
        SWg[i + 1]  = SW[i + 1];  SWPg[i + 1] = vwp;
        kTg[i] = kc;
        if (i == 0) {
            Psg[0] = 0.0; Qsg[0] = 0.0; SWg[0] = 0.0; SWPg[0] = 0.0;
            kTg[Nn] = Nn;
        }
    }
    __syncthreads();

    // S3: rank-merge the 4 sorted key lists (tie-break by list id, then idx)
    {
        float myk; int rank;
        if (tid < 64) {
            myk = k0[tid];
            rank = tid + lb64(k1, myk) + lb64(k2, myk) + lb128(hts, myk);
        } else if (tid < 128) {
            const int j = tid - 64; myk = k1[j];
            rank = j + ub64(k0, myk) + lb64(k2, myk) + lb128(hts, myk);
        } else if (tid < 192) {
            const int j = tid - 128; myk = k2[j];
            rank = j + ub64(k0, myk) + ub64(k1, myk) + lb128(hts, myk);
        } else {
            const int j = tid - 192; myk = hts[j];
            rank = j + ub64(k0, myk) + ub64(k1, myk) + ub64(k2, myk);
        }
        bp[rank] = myk;
    }
    __syncthreads();

    // S4: per-segment payload (s = tid, plus s = NKEY handled by tid 0)
    for (int s = tid; s <= NKEY; s += NKEY) {
        const float t_rep = (s < NKEY) ? bp[s] : (BIGF * 2.0f);
        const int c   = lb64(k0, t_rep);
        const int c0  = lb64(k1, t_rep);
        const int c1  = lb64(k2, t_rep);
        const int cnt = lb128(hts, t_rep);
        const int m = min(c1, kT[c]);
        const double A = Ps[c] * SW[m] - SWP[m];
        const double Q = Qs[c0];
        const int cur = hss[((unsigned)(cnt - 1)) & (unsigned)(Hh - 1)];
        const double eff = (cur == 0) ? 1.0 : -1.0;
        const float  tsl = (s > 0) ? bp[s - 1] : 0.0f;
        const double sE  = exp(-(double)tsl);
        const float As = (float)(wsh2[0] * eff * A * (sE * sE));
        const float Qv = (float)(wsh2[1] * eff * Q * sE);
        pay_all[b * PAYS + s] = make_float4(As, Qv, tsl, 0.0f);
        if (s >= NKEY) break;   // guard tid==0's second lap
    }
    for (int k = tid; k < BPS; k += 320)
        bp_all[b * BPS + k] = bp[k];
}

// ---------------------------------------------------------------------------
// Kernel B: point evaluation.
//   Grid blocks: ONE 9-step search over the merged breakpoints + one float4
//   payload read + 2 expf.  (was: 4 searches = 29 dependent LDS reads,
//   table indirections, 3 expf)
//   Event blocks: unchanged fp64 path over the small tables.
// ---------------------------------------------------------------------------
__global__ __launch_bounds__(256) void eval_kernel(
    const float* __restrict__ times0, const float* __restrict__ times1,
    const float* __restrict__ head_times, const int* __restrict__ head_states,
    const float* __restrict__ base, const float* __restrict__ weights,
    const double* __restrict__ Ps_all, const double* __restrict__ Qs_all,
    const double* __restrict__ SW_all, const double* __restrict__ SWP_all,
    const int* __restrict__ kT_all,
    const float* __restrict__ bp_all, const float4* __restrict__ pay_all,
    double* __restrict__ partials)
{
    __shared__ float  t0s[Nn], t1s[Nn];
    __shared__ float  hts[Hh];
    __shared__ int    hss[Hh];
    __shared__ double Ps[Nn + 1], Qs[Nn + 1], SW[Nn + 1], SWP[Nn + 1];
    __shared__ int    kT[Nn + 1];
    __shared__ double wsh[3];
    __shared__ double redsh[4];
    __shared__ float  bp[BPS];
    __shared__ float4 pay[NKEY + 1];
    __shared__ float  basef;

    const int tid = threadIdx.x;
    const bool isEvent = blockIdx.x >= (unsigned)NGRID;
    const int b = isEvent ? (blockIdx.x - NGRID) : (blockIdx.x >> 4);

    if (isEvent) {
        if (tid < Nn) {
            t0s[tid] = times0[b * Nn + tid];
            t1s[tid] = times1[b * Nn + tid];
        } else if (tid < 192) {
            const int k = tid - 64;
            hts[k] = head_times[b * Hh + k];
            hss[k] = head_states[b * Hh + k];
        } else {
            int k = tid - 192;
            const int base_i = b * TSTRIDE;
            Ps[k]  = Ps_all [base_i + k];
            Qs[k]  = Qs_all [base_i + k];
            SW[k]  = SW_all [base_i + k];
            SWP[k] = SWP_all[base_i + k];
            kT[k]  = kT_all [base_i + k];
            if (tid == 192) {
                k = Nn;
                Ps[k]  = Ps_all [base_i + k];
                Qs[k]  = Qs_all [base_i + k];
                SW[k]  = SW_all [base_i + k];
                SWP[k] = SWP_all[base_i + k];
                kT[k]  = kT_all [base_i + k];
            }
        }
        if (tid == 0) {
            const double w0 = (double)weights[0], w1 = (double)weights[1];
            const double mw = fmax(w0, w1);
            const double e0 = exp(w0 - mw), e1 = exp(w1 - mw);
            wsh[0] = e0 / (e0 + e1);
            wsh[1] = e1 / (e0 + e1);
            wsh[2] = (double)base[0];
        }
    } else {
        for (int k = tid; k < BPS; k += 256) bp[k] = bp_all[b * BPS + k];
        for (int k = tid; k < NKEY + 1; k += 256) pay[k] = pay_all[b * PAYS + k];
        if (tid == 0) basef = base[0];
    }
    __syncthreads();

    double contrib = 0.0;

    if (isEvent) {
        if (tid >= 1 && tid < Hh) {
            const float tf = hts[tid];
            const float thr = tf - TOLf;
            const int c   = lb64(t1s, thr);
            const int c0  = lb64(t0s, thr);
            const int c1  = ub64(t0s, tf);
            const int cnt = lb128(hts, tf);

            const int m = min(c1, kT[c]);
            const double a  = Ps[c] * SW[m] - SWP[m];
            const double ed = exp(-(double)tf);
            const double f0 = a * ed * ed;
            const double f1 = Qs[c0] * ed;
            const int cur = hss[((unsigned)(cnt - 1)) & (unsigned)(Hh - 1)];
            const double eff = (cur == 0) ? 1.0 : -1.0;
            contrib = wsh[2] + eff * (wsh[0] * f0 - wsh[1] * f1);
        }
    } else {
        const int g = ((blockIdx.x & 15) << 8) + tid;
        if (g < Gg) {
            const float tf = (float)g * 0.03f;     // matches reference fp32 grid
            const int seg = lb512(bp, tf);
            const float4 p = pay[seg];             // {As, Qv, tsl, -}
            const float ef = __expf(p.z - tf);     // e^{-(t - tsl)}, dt >= 0
            const float ll = basef + ef * fmaf(ef, p.x, -p.y);
            contrib = -RESd * (double)__expf(ll);
        }
    }

    // block reduction: wave shuffle, then 4-entry LDS
    double v = contrib;
    #pragma unroll
    for (int off = 32; off > 0; off >>= 1) v += __shfl_down(v, off, 64);
    if ((tid & 63) == 0) redsh[tid >> 6] = v;
    __syncthreads();
    if (tid == 0) partials[blockIdx.x] = redsh[0] + redsh[1] + redsh[2] + redsh[3];
}

// ---------------------------------------------------------------------------
// Kernel C: reduce partials -> out
// ---------------------------------------------------------------------------
__global__ __launch_bounds__(256) void finalize_kernel(
    const double* __restrict__ partials, float* __restrict__ out)
{
    __shared__ double redsh[4];
    const int tid = threadIdx.x;
    double v = 0.0;
    for (int i = tid; i < NBLK; i += 256) v += partials[i];
    #pragma unroll
    for (int off = 32; off > 0; off >>= 1) v += __shfl_down(v, off, 64);
    if ((tid & 63) == 0) redsh[tid >> 6] = v;
    __syncthreads();
    if (tid == 0) out[0] = (float)(redsh[0] + redsh[1] + redsh[2] + redsh[3]);
}

extern "C" void kernel_launch(void* const* d_in, const int* in_sizes, int n_in,
                              void* d_out, int out_size, void* d_ws, size_t ws_size,
                              hipStream_t stream) {
    const float* times0      = (const float*)d_in[0];
    const int*   states0     = (const int*)  d_in[1];
    const float* times1      = (const float*)d_in[2];
    const int*   states1     = (const int*)  d_in[3];
    const float* head_times  = (const float*)d_in[4];
    const int*   head_states = (const int*)  d_in[5];
    const float* base        = (const float*)d_in[6];
    const float* weights     = (const float*)d_in[7];

    double* Ps_all  = (double*)d_ws;
    double* Qs_all  = Ps_all  + Bb * TSTRIDE;
    double* SW_all  = Qs_all  + Bb * TSTRIDE;
    double* SWP_all = SW_all  + Bb * TSTRIDE;
    int*    kT_all  = (int*)(SWP_all + Bb * TSTRIDE);
    double* partials = (double*)(kT_all + Bb * TSTRIDE);    // 8B-aligned
    float*  bp_all   = (float*)(partials + NBLK);
    float4* pay_all  = (float4*)(bp_all + Bb * BPS);        // 16B-aligned (all offsets %16==0)

    precompute_kernel<<<Bb, 320, 0, stream>>>(times0, states0, times1, states1,
                                              head_times, head_states, base, weights,
                                              Ps_all, Qs_all, SW_all, SWP_all, kT_all,
                                              bp_all, pay_all);
    eval_kernel<<<NBLK, 256, 0, stream>>>(times0, times1, head_times, head_states,
                                          base, weights,
                                          Ps_all, Qs_all, SW_all, SWP_all, kT_all,
                                          bp_all, pay_all,
                                          partials);
    finalize_kernel<<<1, 256, 0, stream>>>(partials, (float*)d_out);
}